// Round 5
// baseline (824.167 us; speedup 1.0000x reference)
//
#include <hip/hip_runtime.h>
#include <stdint.h>

// Problem: x[B=32][N=8192][D=64] fp32 -> out[B][D][D][D] fp32 (centered 3rd moment)
#define B_SZ 32
#define N_SZ 8192
#define D_SZ 64

typedef _Float16 half8 __attribute__((ext_vector_type(8)));
typedef float f32x4 __attribute__((ext_vector_type(4)));

#define AS1 __attribute__((address_space(1)))
#define AS3 __attribute__((address_space(3)))

#define MFMA16(Aop, Bop, Cop) __builtin_amdgcn_mfma_f32_16x16x32_f16(Aop, Bop, Cop, 0, 0, 0)

// Granule layout v1 (proven 0-conflict in R3): per 64-n granule, chunk (d, cc)
// [8 halves, n = cc*8..+8] stored at d*64 + (cc ^ (d&7))*8 halves.
// ds_read_b128 rule (R3/R4 evidence): conflict-free iff lanes uniform
// 8-per-16B-bank-group; v1's group = c ^ (m&7) satisfies it.

// ---------------------------------------------------------------------------
// Kernel 1: per-batch column sums. grid = 32 b * 32 slabs (256 n-rows each).
// ---------------------------------------------------------------------------
__global__ __launch_bounds__(256) void tp_mean_kernel(const float* __restrict__ x,
                                                      float* __restrict__ sums) {
    const int b    = blockIdx.x >> 5;
    const int slab = blockIdx.x & 31;
    const int d4   = threadIdx.x & 15;
    const int nr   = threadIdx.x >> 4;
    const float* base = x + (size_t)b * (N_SZ * D_SZ) + (size_t)(slab * 256 + nr) * D_SZ + d4 * 4;
    f32x4 s = {0.f, 0.f, 0.f, 0.f};
#pragma unroll
    for (int i = 0; i < 16; i++)
        s += *(const f32x4*)(base + i * 16 * D_SZ);
    __shared__ f32x4 red[16][16];
    red[nr][d4] = s;
    __syncthreads();
    if (threadIdx.x < 16) {
        f32x4 tot = red[0][threadIdx.x];
#pragma unroll
        for (int j = 1; j < 16; j++) tot += red[j][threadIdx.x];
        atomicAdd(&sums[b * 64 + threadIdx.x * 4 + 0], tot[0]);
        atomicAdd(&sums[b * 64 + threadIdx.x * 4 + 1], tot[1]);
        atomicAdd(&sums[b * 64 + threadIdx.x * 4 + 2], tot[2]);
        atomicAdd(&sums[b * 64 + threadIdx.x * 4 + 3], tot[3]);
    }
}

// ---------------------------------------------------------------------------
// Kernel 2: center, cast fp16, register transpose into layout v1 (R3 verbatim).
// ---------------------------------------------------------------------------
__global__ __launch_bounds__(256) void tp_transpose_kernel(const float* __restrict__ x,
                                                           const float* __restrict__ sums,
                                                           _Float16* __restrict__ xcS) {
    const int b    = blockIdx.x >> 6;
    const int tp   = blockIdx.x & 63;
    const int t    = threadIdx.x;
    const int tile = tp * 2 + (t >> 7);
    const int r8   = (t >> 4) & 7;
    const int dq   = t & 15;

    f32x4 mean4 = *(const f32x4*)(sums + b * 64 + dq * 4) * (1.0f / (float)N_SZ);
    const float* src = x + (size_t)b * (N_SZ * D_SZ) + (size_t)(tile * 64 + r8 * 8) * D_SZ + dq * 4;
    f32x4 v[8];
#pragma unroll
    for (int i = 0; i < 8; i++)
        v[i] = *(const f32x4*)(src + i * D_SZ);

    _Float16* dstb = xcS + (size_t)b * (N_SZ * D_SZ) + (size_t)tile * 4096;
#pragma unroll
    for (int c = 0; c < 4; c++) {
        const int d   = dq * 4 + c;
        const int ccp = r8 ^ (d & 7);
        half8 o;
#pragma unroll
        for (int i = 0; i < 8; i++)
            o[i] = (_Float16)(v[i][c] - mean4[c]);
        *(half8*)(dstb + d * 64 + ccp * 8) = o;
    }
}

// ---------------------------------------------------------------------------
// Kernel 3: symmetric batched GEMM. grid = (32 b, 16 eg) so all 16 e-wgs of a
// batch land on one XCD (wgid%8 = b%8 heuristic) -> ~1 HBM copy of xcS.
// wg = 4 waves, wave w = N-quarter; each wave computes ALL 4 e's of the quad
// over its 2048 n. Per 64-n granule: 2 k-steps x (4 A-reads + 4 S-reads ->
// 4e x 10 symmetric-block MFMAs) = 16 ds_read_b128 / 80 MFMA. Double-buffered
// single-barrier pipeline. 4-round cross-wave reduction; wave w stores e0+w.
// ---------------------------------------------------------------------------
__global__ __launch_bounds__(256, 2) void tp_gemm_kernel(const _Float16* __restrict__ xcS,
                                                         float* __restrict__ out) {
    const int b    = blockIdx.x;          // 0..31
    const int eg   = blockIdx.y;          // 0..15
    const int tid  = threadIdx.x;
    const int lane = tid & 63;
    const int wv   = tid >> 6;            // N-quarter 0..3
    const int q    = lane >> 4;           // 0..3
    const int m    = lane & 15;
    const int e0   = eg * 4;

    __shared__ __align__(16) char ldsraw[65536];   // 2 bufs x 4 granules x 8KB
    float* redL = (float*)ldsraw;                  // aliased: 4 x 10KB reduction

    // staging source: wave wv owns granules [wv*32, wv*32+32)
    const _Float16* gq = xcS + (size_t)b * (N_SZ * D_SZ)
                       + (size_t)wv * (32 * 4096) + lane * 8;

    // fragment byte offsets (layout v1): row r chunk c at r*128 + (c^(r&7))*16
    int aOff[2][4], sOff[2][4];
#pragma unroll
    for (int ks = 0; ks < 2; ks++) {
        const int c = ks * 4 + q;
#pragma unroll
        for (int i = 0; i < 4; i++) {
            const int r = i * 16 + m;
            aOff[ks][i] = r * 128 + ((c ^ (r & 7)) * 16);
        }
#pragma unroll
        for (int j = 0; j < 4; j++) {
            const int e = e0 + j;
            sOff[ks][j] = e * 128 + ((c ^ (e & 7)) * 16);
        }
    }

    f32x4 acc[4][10];
#pragma unroll
    for (int ej = 0; ej < 4; ej++)
#pragma unroll
        for (int k = 0; k < 10; k++)
            acc[ej][k] = (f32x4){0.f, 0.f, 0.f, 0.f};

    auto stage = [&](int T, int bi) {
        char* lb = ldsraw + bi * 32768 + wv * 8192;
        const _Float16* gb = gq + (size_t)T * 4096;
#pragma unroll
        for (int k = 0; k < 8; k++)
            __builtin_amdgcn_global_load_lds((const AS1 void*)(gb + k * 512),
                                             (AS3 void*)(lb + k * 1024), 16, 0, 0);
    };

    stage(0, 0);

    for (int T = 0; T < 32; T++) {
        __syncthreads();                  // drains loads for buf[T&1]
        if (T < 31) stage(T + 1, (T + 1) & 1);
        const char* tb = ldsraw + (T & 1) * 32768 + wv * 8192;
#pragma unroll
        for (int ks = 0; ks < 2; ks++) {
            half8 A0 = *(const half8*)(tb + aOff[ks][0]);
            half8 A1 = *(const half8*)(tb + aOff[ks][1]);
            half8 A2 = *(const half8*)(tb + aOff[ks][2]);
            half8 A3 = *(const half8*)(tb + aOff[ks][3]);
            half8 S0 = *(const half8*)(tb + sOff[ks][0]);
            half8 S1 = *(const half8*)(tb + sOff[ks][1]);
            half8 S2 = *(const half8*)(tb + sOff[ks][2]);
            half8 S3 = *(const half8*)(tb + sOff[ks][3]);
#pragma unroll
            for (int ej = 0; ej < 4; ej++) {
                half8 S = (ej == 0) ? S0 : (ej == 1) ? S1 : (ej == 2) ? S2 : S3;
                half8 P0 = A0 * S;        // fold xc[n,e] into A (v_pk_mul_f16)
                half8 P1 = A1 * S;
                half8 P2 = A2 * S;
                half8 P3 = A3 * S;
                acc[ej][0] = MFMA16(P0, A0, acc[ej][0]);
                acc[ej][1] = MFMA16(P0, A1, acc[ej][1]);
                acc[ej][2] = MFMA16(P0, A2, acc[ej][2]);
                acc[ej][3] = MFMA16(P0, A3, acc[ej][3]);
                acc[ej][4] = MFMA16(P1, A1, acc[ej][4]);
                acc[ej][5] = MFMA16(P1, A2, acc[ej][5]);
                acc[ej][6] = MFMA16(P1, A3, acc[ej][6]);
                acc[ej][7] = MFMA16(P2, A2, acc[ej][7]);
                acc[ej][8] = MFMA16(P2, A3, acc[ej][8]);
                acc[ej][9] = MFMA16(P3, A3, acc[ej][9]);
            }
        }
    }

    // 4-round cross-wave reduction: round r, waves != r dump acc[r], wave r sums.
    const float invn = 1.0f / (float)N_SZ;
    float* outb = out + (size_t)b * (D_SZ * D_SZ * D_SZ);
#pragma unroll
    for (int r = 0; r < 4; r++) {
        __syncthreads();
        if (wv != r) {
            float* w = redL + wv * 2560 + lane * 4;
#pragma unroll
            for (int k = 0; k < 10; k++)
                *(f32x4*)(w + k * 256) = acc[r][k];
        }
        __syncthreads();
        if (wv == r) {
#pragma unroll
            for (int u = 0; u < 4; u++) {
                if (u == r) continue;
                const float* rr = redL + u * 2560 + lane * 4;
#pragma unroll
                for (int k = 0; k < 10; k++)
                    acc[r][k] += *(const f32x4*)(rr + k * 256);
            }
        }
    }

    // epilogue: wave wv stores e = e0 + wv from acc[wv].
    {
        const int e = e0 + wv;
        int idx = 0;
#pragma unroll
        for (int i = 0; i < 4; i++) {
#pragma unroll
            for (int j = i; j < 4; j++, idx++) {
                f32x4 vsc = acc[wv][idx] * invn;
#pragma unroll
                for (int rr = 0; rr < 4; rr++)
                    outb[(size_t)(16 * i + q * 4 + rr) * 4096 + e * 64 + 16 * j + m] = vsc[rr];
                if (i != j) {
                    *(f32x4*)&outb[(size_t)(16 * j + m) * 4096 + e * 64 + 16 * i + q * 4] = vsc;
                }
            }
        }
    }
}

// ---------------------------------------------------------------------------
extern "C" void kernel_launch(void* const* d_in, const int* in_sizes, int n_in,
                              void* d_out, int out_size, void* d_ws, size_t ws_size,
                              hipStream_t stream) {
    const float* x = (const float*)d_in[0];
    float* out = (float*)d_out;

    float* sums = (float*)d_ws;                           // 8 KB
    _Float16* xcS = (_Float16*)((char*)d_ws + 8192);      // 33.5 MB fp16

    hipMemsetAsync(sums, 0, B_SZ * D_SZ * sizeof(float), stream);
    tp_mean_kernel<<<dim3(B_SZ * 32), 256, 0, stream>>>(x, sums);
    tp_transpose_kernel<<<dim3(B_SZ * 64), 256, 0, stream>>>(x, sums, xcS);
    tp_gemm_kernel<<<dim3(32, 16), 256, 0, stream>>>(xcS, out);
}

// Round 6
// 247.780 us; speedup vs baseline: 3.3262x; 3.3262x over previous
//
#include <hip/hip_runtime.h>
#include <stdint.h>

// Problem: x[B=32][N=8192][D=64] fp32 -> out[B][D][D][D] fp32 (centered 3rd moment)
#define B_SZ 32
#define N_SZ 8192
#define D_SZ 64

typedef _Float16 half8 __attribute__((ext_vector_type(8)));
typedef float f32x4 __attribute__((ext_vector_type(4)));

#define MFMA16(Aop, Bop, Cop) __builtin_amdgcn_mfma_f32_16x16x32_f16(Aop, Bop, Cop, 0, 0, 0)

// Granule layout (PLAIN, no swizzle — no LDS banks in the GEMM anymore):
// per 64-n granule, chunk (d, cc) [8 halves, n = cc*8..+8] at d*64 + cc*8 halves.
// GEMM A-load (fixed i,ks): lane(q,m) addr = (i*16+m)*128B + (ks*4+q)*16B ->
// 16 lanes per 64B line, fully coalesced L1/L2 hits.

// ---------------------------------------------------------------------------
// Kernel 1: per-batch column sums. grid = 32 b * 32 slabs (256 n-rows each).
// ---------------------------------------------------------------------------
__global__ __launch_bounds__(256) void tp_mean_kernel(const float* __restrict__ x,
                                                      float* __restrict__ sums) {
    const int b    = blockIdx.x >> 5;
    const int slab = blockIdx.x & 31;
    const int d4   = threadIdx.x & 15;
    const int nr   = threadIdx.x >> 4;
    const float* base = x + (size_t)b * (N_SZ * D_SZ) + (size_t)(slab * 256 + nr) * D_SZ + d4 * 4;
    f32x4 s = {0.f, 0.f, 0.f, 0.f};
#pragma unroll
    for (int i = 0; i < 16; i++)
        s += *(const f32x4*)(base + i * 16 * D_SZ);
    __shared__ f32x4 red[16][16];
    red[nr][d4] = s;
    __syncthreads();
    if (threadIdx.x < 16) {
        f32x4 tot = red[0][threadIdx.x];
#pragma unroll
        for (int j = 1; j < 16; j++) tot += red[j][threadIdx.x];
        atomicAdd(&sums[b * 64 + threadIdx.x * 4 + 0], tot[0]);
        atomicAdd(&sums[b * 64 + threadIdx.x * 4 + 1], tot[1]);
        atomicAdd(&sums[b * 64 + threadIdx.x * 4 + 2], tot[2]);
        atomicAdd(&sums[b * 64 + threadIdx.x * 4 + 3], tot[3]);
    }
}

// ---------------------------------------------------------------------------
// Kernel 2: center, cast fp16, register transpose into PLAIN granule layout.
// ---------------------------------------------------------------------------
__global__ __launch_bounds__(256) void tp_transpose_kernel(const float* __restrict__ x,
                                                           const float* __restrict__ sums,
                                                           _Float16* __restrict__ xcS) {
    const int b    = blockIdx.x >> 6;
    const int tp   = blockIdx.x & 63;
    const int t    = threadIdx.x;
    const int tile = tp * 2 + (t >> 7);
    const int r8   = (t >> 4) & 7;       // chunk cc = r8 (n = r8*8..+8)
    const int dq   = t & 15;

    f32x4 mean4 = *(const f32x4*)(sums + b * 64 + dq * 4) * (1.0f / (float)N_SZ);
    const float* src = x + (size_t)b * (N_SZ * D_SZ) + (size_t)(tile * 64 + r8 * 8) * D_SZ + dq * 4;
    f32x4 v[8];
#pragma unroll
    for (int i = 0; i < 8; i++)
        v[i] = *(const f32x4*)(src + i * D_SZ);

    _Float16* dstb = xcS + (size_t)b * (N_SZ * D_SZ) + (size_t)tile * 4096;
#pragma unroll
    for (int c = 0; c < 4; c++) {
        const int d = dq * 4 + c;
        half8 o;
#pragma unroll
        for (int i = 0; i < 8; i++)
            o[i] = (_Float16)(v[i][c] - mean4[c]);
        *(half8*)(dstb + d * 64 + r8 * 8) = o;
    }
}

// ---------------------------------------------------------------------------
// Kernel 3: symmetric batched GEMM, NO LDS staging, NO K-loop barriers.
// grid = (32 b, 16 eg): wgid%8 = b%8 -> all 16 e-wgs of a batch on one XCD,
// whose 2MB xcS slice is L2-resident. wg = 4 waves = (p = e-pair, h = N-half).
// Fragments loaded straight from global (L1/L2 hits), ping-pong prefetched.
// Per granule per wave: 12 global_load_dwordx4 -> 16 pk_mul + 40 MFMA.
// acc[2][10] = 80 regs (R5 lesson: 4-e waves spill). R4-proven epilogue.
// ---------------------------------------------------------------------------
__global__ __launch_bounds__(256, 2) void tp_gemm_kernel(const _Float16* __restrict__ xcS,
                                                         float* __restrict__ out) {
    const int b    = blockIdx.x;          // 0..31
    const int eg   = blockIdx.y;          // 0..15
    const int tid  = threadIdx.x;
    const int lane = tid & 63;
    const int wv   = tid >> 6;            // 0..3
    const int h    = wv & 1;              // N-half
    const int p    = wv >> 1;             // e-pair within quad
    const int q    = lane >> 4;           // 0..3
    const int m    = lane & 15;
    const int e0   = eg * 4 + p * 2;

    __shared__ __align__(16) float redL[10240];   // 40KB, used only post-loop

    const _Float16* gh = xcS + (size_t)b * (N_SZ * D_SZ) + (size_t)h * (N_SZ / 2) * D_SZ;

    // per-lane half-offsets within a granule (plain layout)
    int aoff[4], soff[2];
#pragma unroll
    for (int i = 0; i < 4; i++) aoff[i] = (i * 16 + m) * 64 + q * 8;
#pragma unroll
    for (int j = 0; j < 2; j++) soff[j] = (e0 + j) * 64 + q * 8;

    f32x4 acc[2][10];
#pragma unroll
    for (int ej = 0; ej < 2; ej++)
#pragma unroll
        for (int k = 0; k < 10; k++)
            acc[ej][k] = (f32x4){0.f, 0.f, 0.f, 0.f};

    auto loadg = [&](int t, half8 (&A)[2][4], half8 (&S)[2][2]) {
        const _Float16* gr = gh + (size_t)t * 4096;
#pragma unroll
        for (int ks = 0; ks < 2; ks++) {
#pragma unroll
            for (int i = 0; i < 4; i++)
                A[ks][i] = *(const half8*)(gr + aoff[i] + ks * 32);
#pragma unroll
            for (int j = 0; j < 2; j++)
                S[ks][j] = *(const half8*)(gr + soff[j] + ks * 32);
        }
    };
    auto comp = [&](half8 (&A)[2][4], half8 (&S)[2][2]) {
#pragma unroll
        for (int ks = 0; ks < 2; ks++) {
#pragma unroll
            for (int ej = 0; ej < 2; ej++) {
                half8 Sv = S[ks][ej];
                half8 P0 = A[ks][0] * Sv;   // v_pk_mul_f16: fold xc[n,e] into A
                half8 P1 = A[ks][1] * Sv;
                half8 P2 = A[ks][2] * Sv;
                half8 P3 = A[ks][3] * Sv;
                acc[ej][0] = MFMA16(P0, A[ks][0], acc[ej][0]);
                acc[ej][1] = MFMA16(P0, A[ks][1], acc[ej][1]);
                acc[ej][2] = MFMA16(P0, A[ks][2], acc[ej][2]);
                acc[ej][3] = MFMA16(P0, A[ks][3], acc[ej][3]);
                acc[ej][4] = MFMA16(P1, A[ks][1], acc[ej][4]);
                acc[ej][5] = MFMA16(P1, A[ks][2], acc[ej][5]);
                acc[ej][6] = MFMA16(P1, A[ks][3], acc[ej][6]);
                acc[ej][7] = MFMA16(P2, A[ks][2], acc[ej][7]);
                acc[ej][8] = MFMA16(P2, A[ks][3], acc[ej][8]);
                acc[ej][9] = MFMA16(P3, A[ks][3], acc[ej][9]);
            }
        }
    };

    half8 Aa[2][4], Ab[2][4];
    half8 Sa[2][2], Sb[2][2];
    loadg(0, Aa, Sa);
    for (int t = 0; t < 64; t += 2) {
        if (t + 1 < 64) loadg(t + 1, Ab, Sb);
        comp(Aa, Sa);
        if (t + 2 < 64) loadg(t + 2, Aa, Sa);
        comp(Ab, Sb);
    }

    // cross-h reduction (R4-proven): h==1 waves dump 20 f32x4/lane; h==0 add.
    const int rbase = p * 5120 + lane * 4;
    if (h == 1) {
#pragma unroll
        for (int ej = 0; ej < 2; ej++)
#pragma unroll
            for (int k = 0; k < 10; k++)
                *(f32x4*)(redL + rbase + (ej * 10 + k) * 256) = acc[ej][k];
    }
    __syncthreads();
    if (h == 0) {
#pragma unroll
        for (int ej = 0; ej < 2; ej++)
#pragma unroll
            for (int k = 0; k < 10; k++)
                acc[ej][k] += *(const f32x4*)(redL + rbase + (ej * 10 + k) * 256);

        const float invn = 1.0f / (float)N_SZ;
        float* outb = out + (size_t)b * (D_SZ * D_SZ * D_SZ);
        // C/D layout (verified): col = lane&15 = f-within-block, row = q*4+reg
#pragma unroll
        for (int ej = 0; ej < 2; ej++) {
            const int e = e0 + ej;
            int idx = 0;
#pragma unroll
            for (int i = 0; i < 4; i++) {
#pragma unroll
                for (int j = i; j < 4; j++, idx++) {
                    f32x4 vsc = acc[ej][idx] * invn;
#pragma unroll
                    for (int r = 0; r < 4; r++)
                        outb[(size_t)(16 * i + q * 4 + r) * 4096 + e * 64 + 16 * j + m] = vsc[r];
                    if (i != j) {
                        *(f32x4*)&outb[(size_t)(16 * j + m) * 4096 + e * 64 + 16 * i + q * 4] = vsc;
                    }
                }
            }
        }
    }
}

// ---------------------------------------------------------------------------
extern "C" void kernel_launch(void* const* d_in, const int* in_sizes, int n_in,
                              void* d_out, int out_size, void* d_ws, size_t ws_size,
                              hipStream_t stream) {
    const float* x = (const float*)d_in[0];
    float* out = (float*)d_out;

    float* sums = (float*)d_ws;                           // 8 KB
    _Float16* xcS = (_Float16*)((char*)d_ws + 8192);      // 33.5 MB fp16

    hipMemsetAsync(sums, 0, B_SZ * D_SZ * sizeof(float), stream);
    tp_mean_kernel<<<dim3(B_SZ * 32), 256, 0, stream>>>(x, sums);
    tp_transpose_kernel<<<dim3(B_SZ * 64), 256, 0, stream>>>(x, sums, xcS);
    tp_gemm_kernel<<<dim3(32, 16), 256, 0, stream>>>(xcS, out);
}

// Round 7
// 185.877 us; speedup vs baseline: 4.4339x; 1.3330x over previous
//
#include <hip/hip_runtime.h>
#include <stdint.h>

// Problem: x[B=32][N=8192][D=64] fp32 -> out[B][D][D][D] fp32 (centered 3rd moment)
#define B_SZ 32
#define N_SZ 8192
#define D_SZ 64

typedef _Float16 half8 __attribute__((ext_vector_type(8)));
typedef float f32x4 __attribute__((ext_vector_type(4)));

#define AS1 __attribute__((address_space(1)))
#define AS3 __attribute__((address_space(3)))

#define MFMA16(Aop, Bop, Cop) __builtin_amdgcn_mfma_f32_16x16x32_f16(Aop, Bop, Cop, 0, 0, 0)

// Granule layout v1 (R3/R5-proven 0-conflict): per 64-n granule, chunk (d, cc)
// [8 halves, n = cc*8..+8] stored at d*64 + (cc ^ (d&7))*8 halves.
// R4/R6 lessons baked in: fragments MUST come from LDS (global-direct exposes
// latency once regs run out); pipeline = single barrier + stage(T+1) right
// after it; XCD-local grid (32 b, 16 eg) keeps each batch's 1MB slice in L2.

// ---------------------------------------------------------------------------
// Kernel 1: per-batch column sums. grid = 32 b * 32 slabs (256 n-rows each).
// ---------------------------------------------------------------------------
__global__ __launch_bounds__(256) void tp_mean_kernel(const float* __restrict__ x,
                                                      float* __restrict__ sums) {
    const int b    = blockIdx.x >> 5;
    const int slab = blockIdx.x & 31;
    const int d4   = threadIdx.x & 15;
    const int nr   = threadIdx.x >> 4;
    const float* base = x + (size_t)b * (N_SZ * D_SZ) + (size_t)(slab * 256 + nr) * D_SZ + d4 * 4;
    f32x4 s = {0.f, 0.f, 0.f, 0.f};
#pragma unroll
    for (int i = 0; i < 16; i++)
        s += *(const f32x4*)(base + i * 16 * D_SZ);
    __shared__ f32x4 red[16][16];
    red[nr][d4] = s;
    __syncthreads();
    if (threadIdx.x < 16) {
        f32x4 tot = red[0][threadIdx.x];
#pragma unroll
        for (int j = 1; j < 16; j++) tot += red[j][threadIdx.x];
        atomicAdd(&sums[b * 64 + threadIdx.x * 4 + 0], tot[0]);
        atomicAdd(&sums[b * 64 + threadIdx.x * 4 + 1], tot[1]);
        atomicAdd(&sums[b * 64 + threadIdx.x * 4 + 2], tot[2]);
        atomicAdd(&sums[b * 64 + threadIdx.x * 4 + 3], tot[3]);
    }
}

// ---------------------------------------------------------------------------
// Kernel 2: center, cast fp16, register transpose into layout v1 (R3 verbatim).
// ---------------------------------------------------------------------------
__global__ __launch_bounds__(256) void tp_transpose_kernel(const float* __restrict__ x,
                                                           const float* __restrict__ sums,
                                                           _Float16* __restrict__ xcS) {
    const int b    = blockIdx.x >> 6;
    const int tp   = blockIdx.x & 63;
    const int t    = threadIdx.x;
    const int tile = tp * 2 + (t >> 7);
    const int r8   = (t >> 4) & 7;
    const int dq   = t & 15;

    f32x4 mean4 = *(const f32x4*)(sums + b * 64 + dq * 4) * (1.0f / (float)N_SZ);
    const float* src = x + (size_t)b * (N_SZ * D_SZ) + (size_t)(tile * 64 + r8 * 8) * D_SZ + dq * 4;
    f32x4 v[8];
#pragma unroll
    for (int i = 0; i < 8; i++)
        v[i] = *(const f32x4*)(src + i * D_SZ);

    _Float16* dstb = xcS + (size_t)b * (N_SZ * D_SZ) + (size_t)tile * 4096;
#pragma unroll
    for (int c = 0; c < 4; c++) {
        const int d   = dq * 4 + c;
        const int ccp = r8 ^ (d & 7);
        half8 o;
#pragma unroll
        for (int i = 0; i < 8; i++)
            o[i] = (_Float16)(v[i][c] - mean4[c]);
        *(half8*)(dstb + d * 64 + ccp * 8) = o;
    }
}

// ---------------------------------------------------------------------------
// Kernel 3: symmetric batched GEMM = R4 pipeline + v1 swizzle + XCD grid.
// grid = (32 b, 16 eg): wgid%8 = b%8 -> batch-local XCD, slice L2-resident.
// wg = 4 waves = (p = e-pair, h = N-half). Mega-iter T = 128 n: stage 2
// granules per h-tile into buf[(T+1)&1] right after the single barrier,
// compute from buf[T&1]. Per granule per wave: 12 ds_read_b128 -> 40 MFMA.
// acc[2][10] = 80 regs (4-e waves spill — R5). Cross-h LDS reduction epilogue.
// ---------------------------------------------------------------------------
__global__ __launch_bounds__(256, 2) void tp_gemm_kernel(const _Float16* __restrict__ xcS,
                                                         float* __restrict__ out) {
    const int b    = blockIdx.x;          // 0..31
    const int eg   = blockIdx.y;          // 0..15
    const int tid  = threadIdx.x;
    const int lane = tid & 63;
    const int wv   = tid >> 6;            // 0..3
    const int h    = wv & 1;              // N-half
    const int p    = wv >> 1;             // e-pair within quad
    const int q    = lane >> 4;           // 0..3
    const int m    = lane & 15;
    const int e0   = eg * 4 + p * 2;

    __shared__ __align__(16) char ldsraw[65536];   // 2 bufs x 2 h x 2 granules x 8KB
    float* redL = (float*)ldsraw;                  // aliased for reduction (41KB)

    // staging source: wave (p,h) loads the p-half of each granule of tile h
    const _Float16* gbase = xcS + (size_t)b * (N_SZ * D_SZ)
                          + (size_t)h * (N_SZ / 2) * D_SZ
                          + (size_t)(p * 2048 + lane * 8);

    // fragment byte offsets (layout v1): row r chunk c at r*128 + (c^(r&7))*16
    int aOff[2][4], sOff[2][2];
#pragma unroll
    for (int ks = 0; ks < 2; ks++) {
        const int c = ks * 4 + q;
#pragma unroll
        for (int i = 0; i < 4; i++) {
            const int r = i * 16 + m;
            aOff[ks][i] = r * 128 + ((c ^ (r & 7)) * 16);
        }
#pragma unroll
        for (int j = 0; j < 2; j++) {
            const int e = e0 + j;
            sOff[ks][j] = e * 128 + ((c ^ (e & 7)) * 16);
        }
    }

    f32x4 acc[2][10];
#pragma unroll
    for (int ej = 0; ej < 2; ej++)
#pragma unroll
        for (int k = 0; k < 10; k++)
            acc[ej][k] = (f32x4){0.f, 0.f, 0.f, 0.f};

    // stage mega-tile T into buffer bi: 2 granules (8KB each) of my h-tile
    auto stage = [&](int T, int bi) {
        _Float16* lb = (_Float16*)(ldsraw + bi * 32768 + h * 16384 + p * 4096);
        const _Float16* gb = gbase + (size_t)T * 8192;
#pragma unroll
        for (int g = 0; g < 2; g++)
#pragma unroll
            for (int k = 0; k < 4; k++)
                __builtin_amdgcn_global_load_lds(
                    (const AS1 void*)(gb + g * 4096 + k * 512),
                    (AS3 void*)(lb + g * 4096 + k * 512), 16, 0, 0);
    };

    stage(0, 0);

    for (int T = 0; T < 32; T++) {
        __syncthreads();                  // drains loads for buf[T&1]
        if (T < 31) stage(T + 1, (T + 1) & 1);
        const char* hb = ldsraw + (T & 1) * 32768 + h * 16384;
#pragma unroll
        for (int g = 0; g < 2; g++) {
            const char* tb = hb + g * 8192;
#pragma unroll
            for (int ks = 0; ks < 2; ks++) {
                half8 A0 = *(const half8*)(tb + aOff[ks][0]);
                half8 A1 = *(const half8*)(tb + aOff[ks][1]);
                half8 A2 = *(const half8*)(tb + aOff[ks][2]);
                half8 A3 = *(const half8*)(tb + aOff[ks][3]);
                half8 S0 = *(const half8*)(tb + sOff[ks][0]);
                half8 S1 = *(const half8*)(tb + sOff[ks][1]);
#pragma unroll
                for (int ej = 0; ej < 2; ej++) {
                    half8 S = ej ? S1 : S0;
                    half8 P0 = A0 * S;    // fold xc[n,e] into A (v_pk_mul_f16)
                    half8 P1 = A1 * S;
                    half8 P2 = A2 * S;
                    half8 P3 = A3 * S;
                    acc[ej][0] = MFMA16(P0, A0, acc[ej][0]);
                    acc[ej][1] = MFMA16(P0, A1, acc[ej][1]);
                    acc[ej][2] = MFMA16(P0, A2, acc[ej][2]);
                    acc[ej][3] = MFMA16(P0, A3, acc[ej][3]);
                    acc[ej][4] = MFMA16(P1, A1, acc[ej][4]);
                    acc[ej][5] = MFMA16(P1, A2, acc[ej][5]);
                    acc[ej][6] = MFMA16(P1, A3, acc[ej][6]);
                    acc[ej][7] = MFMA16(P2, A2, acc[ej][7]);
                    acc[ej][8] = MFMA16(P2, A3, acc[ej][8]);
                    acc[ej][9] = MFMA16(P3, A3, acc[ej][9]);
                }
            }
        }
    }
    __syncthreads();                      // before LDS alias reuse

    // cross-h reduction (R4-proven): h==1 waves dump 20 f32x4/lane; h==0 add.
    const int rbase = p * 5120 + lane * 4;
    if (h == 1) {
#pragma unroll
        for (int ej = 0; ej < 2; ej++)
#pragma unroll
            for (int k = 0; k < 10; k++)
                *(f32x4*)(redL + rbase + (ej * 10 + k) * 256) = acc[ej][k];
    }
    __syncthreads();
    if (h == 0) {
#pragma unroll
        for (int ej = 0; ej < 2; ej++)
#pragma unroll
            for (int k = 0; k < 10; k++)
                acc[ej][k] += *(const f32x4*)(redL + rbase + (ej * 10 + k) * 256);

        const float invn = 1.0f / (float)N_SZ;
        float* outb = out + (size_t)b * (D_SZ * D_SZ * D_SZ);
        // C/D layout (verified): col = lane&15 = f-within-block, row = q*4+reg
#pragma unroll
        for (int ej = 0; ej < 2; ej++) {
            const int e = e0 + ej;
            int idx = 0;
#pragma unroll
            for (int i = 0; i < 4; i++) {
#pragma unroll
                for (int j = i; j < 4; j++, idx++) {
                    f32x4 vsc = acc[ej][idx] * invn;
#pragma unroll
                    for (int r = 0; r < 4; r++)
                        outb[(size_t)(16 * i + q * 4 + r) * 4096 + e * 64 + 16 * j + m] = vsc[r];
                    if (i != j) {
                        *(f32x4*)&outb[(size_t)(16 * j + m) * 4096 + e * 64 + 16 * i + q * 4] = vsc;
                    }
                }
            }
        }
    }
}

// ---------------------------------------------------------------------------
extern "C" void kernel_launch(void* const* d_in, const int* in_sizes, int n_in,
                              void* d_out, int out_size, void* d_ws, size_t ws_size,
                              hipStream_t stream) {
    const float* x = (const float*)d_in[0];
    float* out = (float*)d_out;

    float* sums = (float*)d_ws;                           // 8 KB
    _Float16* xcS = (_Float16*)((char*)d_ws + 8192);      // 33.5 MB fp16

    hipMemsetAsync(sums, 0, B_SZ * D_SZ * sizeof(float), stream);
    tp_mean_kernel<<<dim3(B_SZ * 32), 256, 0, stream>>>(x, sums);
    tp_transpose_kernel<<<dim3(B_SZ * 64), 256, 0, stream>>>(x, sums, xcS);
    tp_gemm_kernel<<<dim3(32, 16), 256, 0, stream>>>(xcS, out);
}